// Round 21
// baseline (257.662 us; speedup 1.0000x reference)
//
#include <hip/hip_runtime.h>

#define NNODE 6144
#define FEATD 512
#define HIDD  512
#define NCLSD 64
#define NMSK  (NNODE/64)   // 96 mask words per row
#define NKT   (NNODE/32)   // 192 k-tiles (node dim)
#define NKTX  (FEATD/32)   // 16 k-tiles (feature dim)
#define LALPHA 0.2f

typedef unsigned short ushort_t;
typedef unsigned char u8_t;
typedef unsigned long long u64_t;
typedef short bf16x8 __attribute__((ext_vector_type(8)));
typedef float f32x4 __attribute__((ext_vector_type(4)));

__device__ __forceinline__ float lrelu(float x){ return x > 0.f ? x : LALPHA * x; }

__device__ __forceinline__ ushort_t f2b(float x){
    union { float f; unsigned u; } v; v.f = x;
    unsigned r = v.u + 0x7fffu + ((v.u >> 16) & 1u);
    return (ushort_t)(r >> 16);
}
__device__ __forceinline__ float b2f(ushort_t u){
    union { unsigned u; float f; } v; v.u = ((unsigned)u) << 16; return v.f;
}

// Runtime C/D-layout calibration (round-8 validated)
__device__ __forceinline__ void calib_cd(int lm, int* qrow, int* vcol){
    bf16x8 ai, as;
    ushort_t vi = f2b((float)(lm + 1));
    ushort_t vs = f2b(0.03125f);
    #pragma unroll
    for (int e = 0; e < 8; e++){ ((ushort_t*)&ai)[e] = vi; ((ushort_t*)&as)[e] = vs; }
    f32x4 z = {0.f, 0.f, 0.f, 0.f};
    f32x4 d1 = __builtin_amdgcn_mfma_f32_16x16x32_bf16(ai, as, z, 0, 0, 0);
    f32x4 d2 = __builtin_amdgcn_mfma_f32_16x16x32_bf16(as, ai, z, 0, 0, 0);
    #pragma unroll
    for (int r = 0; r < 4; r++){
        qrow[r] = (int)(d1[r] + 0.5f) - 1;
        vcol[r] = (int)(d2[r] + 0.5f) - 1;
    }
}

// ---------------- adj (int32) -> bitmask (fallback path only) ----------------
__global__ void k_adjmask(const int* __restrict__ adj, u64_t* __restrict__ mask){
    int lane = threadIdx.x & 63;
    size_t wid = ((size_t)blockIdx.x * blockDim.x + threadIdx.x) >> 6;
    size_t nw = (size_t)NNODE * NNODE / 64;
    size_t stride = ((size_t)gridDim.x * blockDim.x) >> 6;
    for (size_t q = wid; q < nw; q += stride){
        int a = adj[q * 64 + lane];
        u64_t b = __ballot(a > 0);
        if (lane == 0) mask[q] = b;
    }
}

// ---------------- fold helper ----------------
__device__ __forceinline__ void fold_rows(const float* W, const float* a,
        float* out1, float* out2, int K, int blk, int tid){
    int row  = (blk * 256 + tid) >> 6;
    int lane = tid & 63;
    const float* wr = W + (size_t)row * K;
    float s1 = 0.f, s2 = 0.f;
    for (int c = lane; c < K; c += 64){ float w = wr[c]; s1 += w * a[c]; s2 += w * a[K + c]; }
    #pragma unroll
    for (int m = 32; m; m >>= 1){ s1 += __shfl_xor(s1, m); s2 += __shfl_xor(s2, m); }
    if (lane == 0){ out1[row] = s1; out2[row] = s2; }
}

// ---------------- fused prep: fold(Wg), fold(Wt), WgF, WoF ----------------
__global__ __launch_bounds__(256) void k_prep(const float* __restrict__ Wg,
        const float* __restrict__ ag, const float* __restrict__ Wt,
        const float* __restrict__ at, const float* __restrict__ Wo,
        ushort_t* __restrict__ WgF, ushort_t* __restrict__ WoF,
        float* __restrict__ wg1, float* __restrict__ wg2,
        float* __restrict__ wt1, float* __restrict__ wt2){
    int b = blockIdx.x, tid = threadIdx.x;
    if (b < 128){
        fold_rows(Wg, ag, wg1, wg2, HIDD, b, tid);
    } else if (b < 256){
        fold_rows(Wt, at, wt1, wt2, HIDD, b - 128, tid);
    } else if (b < 384){
        int gid = (b - 256) * 256 + tid;
        int l = gid & 63, unit = gid >> 6;
        int ci = unit / NKTX, ki = unit - ci * NKTX;
        int lm = l & 15, lh = l >> 4;
        bf16x8 pk;
        #pragma unroll
        for (int e = 0; e < 8; e++)
            ((ushort_t*)&pk)[e] = f2b(Wg[(size_t)(ki*32 + lh*8 + e) * HIDD + ci*16 + lm]);
        *(bf16x8*)(WgF + (size_t)unit * 512 + (size_t)l * 8) = pk;
    } else {
        int gid = (b - 384) * 256 + tid;
        if (gid >= (NCLSD/16) * NKTX * 64) return;
        int l = gid & 63, unit = gid >> 6;
        int ci = unit / NKTX, ki = unit - ci * NKTX;
        int lm = l & 15, lh = l >> 4;
        bf16x8 pk;
        #pragma unroll
        for (int e = 0; e < 8; e++)
            ((ushort_t*)&pk)[e] = f2b(Wo[(size_t)(ki*32 + lh*8 + e) * NCLSD + ci*16 + lm]);
        *(bf16x8*)(WoF + (size_t)unit * 512 + (size_t)l * 8) = pk;
    }
}

// ---------------- o1/o2 = A @ {v1,v2}  (one wave per row) ----------------
__global__ void k_rowvec2_f32(const float* __restrict__ A, const float* __restrict__ v1,
                              const float* __restrict__ v2, float* __restrict__ o1,
                              float* __restrict__ o2, int K){
    int row  = (blockIdx.x * blockDim.x + threadIdx.x) >> 6;
    int lane = threadIdx.x & 63;
    const float* r = A + (size_t)row * K;
    float s1 = 0.f, s2 = 0.f;
    for (int c = lane; c < K; c += 64){ float x = r[c]; s1 += x * v1[c]; s2 += x * v2[c]; }
    #pragma unroll
    for (int m = 32; m; m >>= 1){ s1 += __shfl_xor(s1, m); s2 += __shfl_xor(s2, m); }
    if (lane == 0){ o1[row] = s1; o2[row] = s2; }
}

// ---------------- *out = max(x[0..n))  (fallback path only) ----------------
__global__ void k_max(const float* __restrict__ x, int n, float* __restrict__ out){
    __shared__ float sm[16];
    float m = -3.0e38f;
    for (int i = threadIdx.x; i < n; i += blockDim.x) m = fmaxf(m, x[i]);
    #pragma unroll
    for (int s = 32; s; s >>= 1) m = fmaxf(m, __shfl_xor(m, s));
    if ((threadIdx.x & 63) == 0) sm[threadIdx.x >> 6] = m;
    __syncthreads();
    if (threadIdx.x == 0){
        float mm = sm[0];
        for (int i = 1; i < (int)(blockDim.x >> 6); i++) mm = fmaxf(mm, sm[i]);
        *out = mm;
    }
}

// ---------------- fused: X -> XF fragments + e1/e2 scores ----------------
__global__ __launch_bounds__(256) void k_xprep(const float* __restrict__ X,
        const float* __restrict__ wg1, const float* __restrict__ wg2,
        ushort_t* __restrict__ XF, float* __restrict__ e1, float* __restrict__ e2){
    __shared__ float w1s[FEATD], w2s[FEATD];
    int ri = blockIdx.x;
    int tid = threadIdx.x;
    int r = tid >> 4, q = tid & 15;
    for (int k = tid; k < FEATD; k += 256){ w1s[k] = wg1[k]; w2s[k] = wg2[k]; }
    __syncthreads();
    const float* xp = X + (size_t)(ri * 16 + r) * FEATD;
    ushort_t* xb = XF + (size_t)ri * NKTX * 512;
    float s1 = 0.f, s2 = 0.f;
    for (int j0 = 0; j0 < FEATD; j0 += 128){
        int j = j0 + q * 8;
        float4 fA = *(const float4*)(xp + j);
        float4 fB = *(const float4*)(xp + j + 4);
        float xa[8] = {fA.x, fA.y, fA.z, fA.w, fB.x, fB.y, fB.z, fB.w};
        bf16x8 pk;
        #pragma unroll
        for (int e = 0; e < 8; e++){
            ((ushort_t*)&pk)[e] = f2b(xa[e]);
            s1 += xa[e] * w1s[j + e];
            s2 += xa[e] * w2s[j + e];
        }
        int ki = j >> 5;
        int lh = (j >> 3) & 3;
        *(bf16x8*)(xb + ((size_t)ki * 512 + (size_t)(r + (lh << 4)) * 8)) = pk;
    }
    #pragma unroll
    for (int o = 8; o; o >>= 1){ s1 += __shfl_xor(s1, o); s2 += __shfl_xor(s2, o); }
    if (q == 0){
        int row = ri * 16 + r;
        e1[row] = s1; e2[row] = s2;
    }
}

// ---------------- device: gemm_xw body (512 thr) ----------------
__device__ __forceinline__ void dev_gemm_xw(int ri, int tid,
        const ushort_t* XF, const ushort_t* WgF, ushort_t* VF){
    int i0 = ri * 16;
    int w = tid >> 6, l = tid & 63, lm = l & 15;
    int c0 = w * 64;
    int qrow[4], vcol[4];
    calib_cd(lm, qrow, vcol);
    f32x4 acc[4] = {};
    const ushort_t* Ap = XF + (size_t)ri * NKTX * 512 + l * 8;
    const ushort_t* Bp[4];
    #pragma unroll
    for (int t = 0; t < 4; t++)
        Bp[t] = WgF + (size_t)((c0 >> 4) + t) * NKTX * 512 + l * 8;
    for (int ki = 0; ki < NKTX; ki++){
        bf16x8 af = *(const bf16x8*)(Ap + (size_t)ki * 512);
        #pragma unroll
        for (int t = 0; t < 4; t++){
            bf16x8 bf = *(const bf16x8*)(Bp[t] + (size_t)ki * 512);
            acc[t] = __builtin_amdgcn_mfma_f32_16x16x32_bf16(af, bf, acc[t], 0, 0, 0);
        }
    }
    #pragma unroll
    for (int t = 0; t < 4; t++){
        int ci = (c0 >> 4) + t;
        #pragma unroll
        for (int r = 0; r < 4; r++){
            int node = i0 + qrow[r];
            size_t vo = ((size_t)ci * NKT + (node >> 5)) * 512
                      + (size_t)(vcol[r] + ((node >> 3) & 3) * 16) * 8 + (node & 7);
            VF[vo] = f2b(acc[t][r]);
        }
    }
}

// ---------------- k_mid: interleaved gemm_xw (even bids) + pgen (odd bids) ----------------
__global__ __launch_bounds__(512) void k_mid(const ushort_t* __restrict__ XF,
        const ushort_t* __restrict__ WgF, ushort_t* __restrict__ VF,
        const int* __restrict__ adj, const float* __restrict__ e1,
        const float* __restrict__ e2, ushort_t* __restrict__ PF,
        float* __restrict__ lsum, u8_t* __restrict__ mask8){
    __shared__ float e2s[NNODE];
    __shared__ float mred[8];
    int bid = blockIdx.x;
    int tid = threadIdx.x;
    if ((bid & 1) == 0){            // gemm_xw half
        dev_gemm_xw(bid >> 1, tid, XF, WgF, VF);
        return;
    }
    // ---- pgen half (512 threads: r=tid>>5, q=tid&31) ----
    int ri = bid >> 1;
    int i0 = ri * 16;
    int r = tid >> 5, q = tid & 31;
    for (int k = tid; k < NNODE; k += 512) e2s[k] = e2[k];
    __syncthreads();
    float mx = -3.0e38f;
    for (int k = tid; k < NNODE; k += 512) mx = fmaxf(mx, e2s[k]);
    #pragma unroll
    for (int o = 32; o; o >>= 1) mx = fmaxf(mx, __shfl_xor(mx, o));
    if ((tid & 63) == 0) mred[tid >> 6] = mx;
    __syncthreads();
    float e2m = mred[0];
    #pragma unroll
    for (int z = 1; z < 8; z++) e2m = fmaxf(e2m, mred[z]);
    float e1i = e1[i0 + r];
    float M = lrelu(e1i + e2m);   // exact upper bound (softmax shift-invariant)
    float rsum = 0.f;
    ushort_t* pfb = PF + (size_t)ri * NKT * 512;
    const int* adjp = adj + (size_t)(i0 + r) * NNODE;
    u8_t* mrow = mask8 + (size_t)(i0 + r) * (NMSK * 8);
    for (int j0 = 0; j0 < NNODE; j0 += 256){
        int j = j0 + q * 8;
        int4 a0 = *(const int4*)(adjp + j);
        int4 a1 = *(const int4*)(adjp + j + 4);
        int av[8] = {a0.x, a0.y, a0.z, a0.w, a1.x, a1.y, a1.z, a1.w};
        float4 fA = *(const float4*)&e2s[j];
        float4 fB = *(const float4*)&e2s[j + 4];
        float ea[8] = {fA.x, fA.y, fA.z, fA.w, fB.x, fB.y, fB.z, fB.w};
        bf16x8 pk;
        unsigned byte = 0;
        #pragma unroll
        for (int e = 0; e < 8; e++){
            int bit = av[e] > 0;
            byte |= (unsigned)bit << e;
            float p = bit ? __expf(lrelu(e1i + ea[e]) - M) : 0.f;
            ushort_t pb = f2b(p);
            ((ushort_t*)&pk)[e] = pb;
            rsum += b2f(pb);
        }
        mrow[j >> 3] = (u8_t)byte;
        int ki = j >> 5;
        int lh = (j >> 3) & 3;
        *(bf16x8*)(pfb + ((size_t)ki * 512 + (size_t)(r + (lh << 4)) * 8)) = pk;
    }
    #pragma unroll
    for (int o = 16; o; o >>= 1) rsum += __shfl_xor(rsum, o);
    if (q == 0) lsum[i0 + r] = rsum;
}

// ---------------- standalone gemm_xw (fallback path) ----------------
__global__ __launch_bounds__(512) void k_gemm_xw(const ushort_t* __restrict__ XF,
        const ushort_t* __restrict__ WgF, ushort_t* __restrict__ VF){
    dev_gemm_xw(blockIdx.x, threadIdx.x, XF, WgF, VF);
}

// ---------------- k_l2prep: gemm_out (b<96) + rowvec2(res·wt) (b>=96) ----------------
__global__ __launch_bounds__(256) void k_l2prep(const float* __restrict__ res,
        const ushort_t* __restrict__ WoF, float* __restrict__ Wh2,
        ushort_t* __restrict__ VF2, const float* __restrict__ wt1,
        const float* __restrict__ wt2, float* __restrict__ t1v, float* __restrict__ t2v){
    int b = blockIdx.x, tid = threadIdx.x;
    if (b >= 96){
        // rowvec2: t1/t2 = res @ {wt1, wt2}
        int row  = ((b - 96) * 256 + tid) >> 6;
        int lane = tid & 63;
        const float* r = res + (size_t)row * HIDD;
        float s1 = 0.f, s2 = 0.f;
        for (int c = lane; c < HIDD; c += 64){ float x = r[c]; s1 += x * wt1[c]; s2 += x * wt2[c]; }
        #pragma unroll
        for (int m = 32; m; m >>= 1){ s1 += __shfl_xor(s1, m); s2 += __shfl_xor(s2, m); }
        if (lane == 0){ t1v[row] = s1; t2v[row] = s2; }
        return;
    }
    // gemm_out: Wh2 = res @ Wo (MFMA), emits fp32 Wh2 + fragment VF2
    int w = tid >> 6, l = tid & 63, lm = l & 15, lh = l >> 4;
    int i0 = b * 64 + w * 16;
    int qrow[4], vcol[4];
    calib_cd(lm, qrow, vcol);
    f32x4 acc[4] = {};
    const float* ap = res + (size_t)(i0 + lm) * HIDD + lh * 8;
    for (int k0 = 0; k0 < HIDD; k0 += 32){
        int ki = k0 >> 5;
        float4 x0 = *(const float4*)(ap + k0);
        float4 x1 = *(const float4*)(ap + k0 + 4);
        float xa[8] = {x0.x, x0.y, x0.z, x0.w, x1.x, x1.y, x1.z, x1.w};
        bf16x8 af;
        #pragma unroll
        for (int e = 0; e < 8; e++) ((ushort_t*)&af)[e] = f2b(xa[e]);
        #pragma unroll
        for (int t = 0; t < 4; t++){
            bf16x8 bf = *(const bf16x8*)(WoF + (size_t)(t * NKTX + ki) * 512 + l * 8);
            acc[t] = __builtin_amdgcn_mfma_f32_16x16x32_bf16(af, bf, acc[t], 0, 0, 0);
        }
    }
    #pragma unroll
    for (int t = 0; t < 4; t++){
        #pragma unroll
        for (int r = 0; r < 4; r++){
            int node = i0 + qrow[r], col = t*16 + vcol[r];
            float v = acc[t][r];
            Wh2[(size_t)node * NCLSD + col] = v;
            size_t vo = ((size_t)t * NKT + (node >> 5)) * 512
                      + (size_t)(vcol[r] + ((node >> 3) & 3) * 16) * 8 + (node & 7);
            VF2[vo] = f2b(v);
        }
    }
}

// ---------------- GAT1 GEMM: XCD swizzle + banked 2-deep loop ----------------
__global__ __launch_bounds__(256) void k_gat1g(const ushort_t* __restrict__ PF,
        const float* __restrict__ lsum, const ushort_t* __restrict__ VF,
        float* __restrict__ res){
    int bid = blockIdx.x;
    int xcd = bid & 7;
    int k   = bid >> 3;
    int c8  = k & 7;
    int rg  = (k >> 3) * 8 + xcd;
    int tid = threadIdx.x;
    int w = tid >> 6, l = tid & 63, lm = l & 15;
    int ri = rg * 4 + w;
    int i0 = ri * 16;
    int cbase = c8 * 64;
    int qrow[4], vcol[4];
    calib_cd(lm, qrow, vcol);
    f32x4 acc[4] = {};
    const ushort_t* Ap = PF + (size_t)ri * NKT * 512 + l * 8;
    const ushort_t* Vp[4];
    #pragma unroll
    for (int t = 0; t < 4; t++)
        Vp[t] = VF + (size_t)(c8 * 4 + t) * NKT * 512 + l * 8;
    bf16x8 aA, aB, vA[4], vB[4];
    aA = *(const bf16x8*)(Ap);
    #pragma unroll
    for (int t = 0; t < 4; t++) vA[t] = *(const bf16x8*)(Vp[t]);
    for (int kt = 0; kt < NKT; kt += 2){
        size_t ob = (size_t)(kt + 1) * 512;
        aB = *(const bf16x8*)(Ap + ob);
        #pragma unroll
        for (int t = 0; t < 4; t++) vB[t] = *(const bf16x8*)(Vp[t] + ob);
        #pragma unroll
        for (int t = 0; t < 4; t++)
            acc[t] = __builtin_amdgcn_mfma_f32_16x16x32_bf16(aA, vA[t], acc[t], 0, 0, 0);
        int k2 = (kt + 2 < NKT) ? kt + 2 : 0;
        size_t oa = (size_t)k2 * 512;
        aA = *(const bf16x8*)(Ap + oa);
        #pragma unroll
        for (int t = 0; t < 4; t++) vA[t] = *(const bf16x8*)(Vp[t] + oa);
        #pragma unroll
        for (int t = 0; t < 4; t++)
            acc[t] = __builtin_amdgcn_mfma_f32_16x16x32_bf16(aB, vB[t], acc[t], 0, 0, 0);
    }
    float den[4];
    #pragma unroll
    for (int r = 0; r < 4; r++) den[r] = lsum[i0 + qrow[r]];
    #pragma unroll
    for (int t = 0; t < 4; t++){
        #pragma unroll
        for (int r = 0; r < 4; r++){
            int row = qrow[r];
            int col = cbase + t*16 + vcol[r];
            float v = acc[t][r] / den[r];
            v = v > 0.f ? v : expm1f(v);   // elu
            res[(size_t)(i0 + row) * HIDD + col] = v;
        }
    }
}

// ---------------- GAT layer 1 fallback (register P, VF layout) ----------------
__global__ __launch_bounds__(256) void k_gat1(const u64_t* __restrict__ mask,
        const float* __restrict__ e1, const float* __restrict__ e2,
        const float* __restrict__ e2max,
        const ushort_t* __restrict__ VF, float* __restrict__ res){
    __shared__ __align__(16) float e2s[NNODE];
    __shared__ u64_t msk[16][NMSK + 1];
    int bid = blockIdx.x;
    int b8 = bid & 7, a = bid >> 3;
    int ch = b8 >> 2;
    int rg = a * 4 + (b8 & 3);
    int i0 = rg * 16;
    int tid = threadIdx.x;
    int w = tid >> 6, l = tid & 63, lm = l & 15, lh = l >> 4;
    int cbase = ch * 256 + w * 64;
    int qrow[4], vcol[4];
    calib_cd(lm, qrow, vcol);
    for (int k = tid; k < NNODE; k += 256) e2s[k] = e2[k];
    for (int k = tid; k < 16 * NMSK; k += 256) msk[k / NMSK][k % NMSK] = mask[(size_t)i0 * NMSK + k];
    __syncthreads();
    float e1i = e1[i0 + lm];
    float M = lrelu(e1i + *e2max);
    float lsum = 0.f;
    f32x4 acc[4] = {};
    const ushort_t* Vp[4];
    #pragma unroll
    for (int t = 0; t < 4; t++)
        Vp[t] = VF + (size_t)((cbase >> 4) + t) * NKT * 512 + l * 8;
    bf16x8 vc[4][2], vn[4][2];
    #pragma unroll
    for (int t = 0; t < 4; t++)
        #pragma unroll
        for (int h = 0; h < 2; h++) vc[t][h] = *(const bf16x8*)(Vp[t] + h * 512);
    for (int j0 = 0; j0 < NNODE; j0 += 64){
        u64_t word = msk[lm][j0 >> 6];
        int jn = j0 + 64;
        if (jn < NNODE){
            size_t nb = (size_t)(jn >> 5) * 512;
            #pragma unroll
            for (int t = 0; t < 4; t++)
                #pragma unroll
                for (int h = 0; h < 2; h++) vn[t][h] = *(const bf16x8*)(Vp[t] + nb + h * 512);
        }
        #pragma unroll
        for (int h = 0; h < 2; h++){
            int jb = j0 + h*32 + lh*8;
            float4 fA = *(const float4*)&e2s[jb];
            float4 fB = *(const float4*)&e2s[jb + 4];
            float ea[8] = {fA.x, fA.y, fA.z, fA.w, fB.x, fB.y, fB.z, fB.w};
            int sh = h*32 + lh*8;
            bf16x8 pk;
            float ls = 0.f;
            #pragma unroll
            for (int e = 0; e < 8; e++){
                float p = ((word >> (sh + e)) & 1ull) ? __expf(lrelu(e1i + ea[e]) - M) : 0.f;
                ushort_t pb = f2b(p);
                ((ushort_t*)&pk)[e] = pb;
                ls += b2f(pb);
            }
            lsum += ls;
            #pragma unroll
            for (int t = 0; t < 4; t++)
                acc[t] = __builtin_amdgcn_mfma_f32_16x16x32_bf16(pk, vc[t][h], acc[t], 0, 0, 0);
        }
        #pragma unroll
        for (int t = 0; t < 4; t++)
            #pragma unroll
            for (int h = 0; h < 2; h++) vc[t][h] = vn[t][h];
    }
    lsum += __shfl_xor(lsum, 16);
    lsum += __shfl_xor(lsum, 32);
    #pragma unroll
    for (int t = 0; t < 4; t++){
        #pragma unroll
        for (int r = 0; r < 4; r++){
            float den = __shfl(lsum, qrow[r]);
            int row = qrow[r];
            int col = cbase + t*16 + vcol[r];
            float v = acc[t][r] / den;
            v = v > 0.f ? v : expm1f(v);
            res[(size_t)(i0 + row) * HIDD + col] = v;
        }
    }
}

// ---------------- GAT layer 2 + fused log_softmax (internal maxes) ----------------
#define JSPAN (NNODE/8)
__global__ __launch_bounds__(512) void k_gat2(const u64_t* __restrict__ mask,
        const float* __restrict__ o1, const float* __restrict__ o2,
        const float* __restrict__ t1, const float* __restrict__ t2,
        const ushort_t* __restrict__ VF2, float* __restrict__ out){
    __shared__ float accs[8][16][64];
    __shared__ float lsums[8][16];
    __shared__ u64_t msk[16][NMSK + 1];
    __shared__ float mred[16];
    int i0 = blockIdx.x * 16;
    int tid = threadIdx.x;
    int w = tid >> 6, l = tid & 63, lm = l & 15, lh = l >> 4;
    for (int k = tid; k < 16 * NMSK; k += 512) msk[k / NMSK][k % NMSK] = mask[(size_t)i0 * NMSK + k];
    float mo = -3.0e38f, mt = -3.0e38f;
    for (int k = tid; k < NNODE; k += 512){ mo = fmaxf(mo, o2[k]); mt = fmaxf(mt, t2[k]); }
    #pragma unroll
    for (int o = 32; o; o >>= 1){ mo = fmaxf(mo, __shfl_xor(mo, o)); mt = fmaxf(mt, __shfl_xor(mt, o)); }
    if (l == 0){ mred[w * 2] = mo; mred[w * 2 + 1] = mt; }
    __syncthreads();
    float o2m = -3.0e38f, t2m = -3.0e38f;
    #pragma unroll
    for (int q = 0; q < 8; q++){ o2m = fmaxf(o2m, mred[q * 2]); t2m = fmaxf(t2m, mred[q * 2 + 1]); }
    int qrow[4], vcol[4];
    calib_cd(lm, qrow, vcol);
    int jbase = w * JSPAN;
    float o1v = o1[i0 + lm], t1v = t1[i0 + lm];
    float M = lrelu(o1v + o2m) + lrelu(t1v + t2m);
    float lsum = 0.f;
    f32x4 acc[4] = {};
    const float* o2p = o2 + jbase + lh * 8;
    const float* t2p = t2 + jbase + lh * 8;
    float4 oA = *(const float4*)(o2p), oB = *(const float4*)(o2p + 4);
    float4 tA = *(const float4*)(t2p), tB = *(const float4*)(t2p + 4);
    const u8_t* mrow = (const u8_t*)&msk[lm][0];
    const ushort_t* Vp[4];
    #pragma unroll
    for (int t = 0; t < 4; t++)
        Vp[t] = VF2 + (size_t)t * NKT * 512 + (size_t)(jbase >> 5) * 512 + l * 8;
    bf16x8 vcur[4], vnxt[4];
    #pragma unroll
    for (int t = 0; t < 4; t++) vcur[t] = *(const bf16x8*)(Vp[t]);

    for (int js = 0; js < JSPAN; js += 32){
        unsigned b8v = mrow[(jbase + js + lh * 8) >> 3];
        float oa[8] = {oA.x, oA.y, oA.z, oA.w, oB.x, oB.y, oB.z, oB.w};
        float ta[8] = {tA.x, tA.y, tA.z, tA.w, tB.x, tB.y, tB.z, tB.w};
        bf16x8 pk;
        float ls = 0.f;
        #pragma unroll
        for (int e = 0; e < 8; e++){
            float p = ((b8v >> e) & 1u) ?
                      __expf(lrelu(o1v + oa[e]) + lrelu(t1v + ta[e]) - M) : 0.f;
            ushort_t pb = f2b(p);
            ((ushort_t*)&pk)[e] = pb;
            ls += b2f(pb);
        }
        lsum += ls;
        int jn = js + 32;
        if (jn < JSPAN){
            oA = *(const float4*)(o2p + jn); oB = *(const float4*)(o2p + jn + 4);
            tA = *(const float4*)(t2p + jn); tB = *(const float4*)(t2p + jn + 4);
            #pragma unroll
            for (int t = 0; t < 4; t++)
                vnxt[t] = *(const bf16x8*)(Vp[t] + (size_t)(jn >> 5) * 512);
        }
        #pragma unroll
        for (int t = 0; t < 4; t++)
            acc[t] = __builtin_amdgcn_mfma_f32_16x16x32_bf16(pk, vcur[t], acc[t], 0, 0, 0);
        #pragma unroll
        for (int t = 0; t < 4; t++) vcur[t] = vnxt[t];
    }
    lsum += __shfl_xor(lsum, 16);
    lsum += __shfl_xor(lsum, 32);
    if (lh == 0) lsums[w][lm] = lsum;
    #pragma unroll
    for (int t = 0; t < 4; t++)
        #pragma unroll
        for (int r = 0; r < 4; r++)
            accs[w][qrow[r]][t*16 + vcol[r]] = acc[t][r];
    __syncthreads();
    #pragma unroll
    for (int rr = 0; rr < 2; rr++){
        int row = w * 2 + rr;
        float den = 0.f, v = 0.f;
        #pragma unroll
        for (int q = 0; q < 8; q++){ den += lsums[q][row]; v += accs[q][row][l]; }
        float val = v / den;
        float mx = val;
        #pragma unroll
        for (int o = 32; o; o >>= 1) mx = fmaxf(mx, __shfl_xor(mx, o));
        float ex = __expf(val - mx);
        #pragma unroll
        for (int o = 32; o; o >>= 1) ex += __shfl_xor(ex, o);
        out[(size_t)(i0 + row) * NCLSD + l] = val - mx - logf(ex);
    }
}

// ---------------- row-wise log_softmax (fallback path only) ----------------
__global__ void k_logsoftmax(const float* __restrict__ out2, float* __restrict__ out){
    int w = threadIdx.x >> 6, l = threadIdx.x & 63;
    int row = blockIdx.x * 4 + w;
    float v = out2[(size_t)row * NCLSD + l];
    float mx = v;
    #pragma unroll
    for (int o = 32; o; o >>= 1) mx = fmaxf(mx, __shfl_xor(mx, o));
    float ex = __expf(v - mx);
    #pragma unroll
    for (int o = 32; o; o >>= 1) ex += __shfl_xor(ex, o);
    out[(size_t)row * NCLSD + l] = v - mx - logf(ex);
}

// ---------------- launch ----------------
extern "C" void kernel_launch(void* const* d_in, const int* in_sizes, int n_in,
                              void* d_out, int out_size, void* d_ws, size_t ws_size,
                              hipStream_t stream){
    const float* X   = (const float*)d_in[0];
    const int*   adj = (const int*)d_in[1];
    const float* Wg  = (const float*)d_in[2];
    const float* ag  = (const float*)d_in[3];
    const float* Wt  = (const float*)d_in[4];
    const float* at  = (const float*)d_in[5];
    const float* Wo  = (const float*)d_in[6];
    const float* ao  = (const float*)d_in[7];
    float* out = (float*)d_out;

    char* ws = (char*)d_ws;
    size_t off = 0;
    auto take = [&](size_t n){ char* p = ws + off; off = (off + n + 255) & ~(size_t)255; return p; };
    u64_t*    maskb = (u64_t*)take((size_t)NNODE * NMSK * 8);
    ushort_t* VF    = (ushort_t*)take((size_t)HIDD * NNODE * 2);
    float*    res   = (float*)take((size_t)NNODE * HIDD * 4);
    float*    Wh2   = (float*)take((size_t)NNODE * NCLSD * 4);
    ushort_t* VF2   = (ushort_t*)take((size_t)NCLSD * NNODE * 2);
    ushort_t* XF    = (ushort_t*)take((size_t)NNODE * FEATD * 2);
    ushort_t* WgF   = (ushort_t*)take((size_t)FEATD * HIDD * 2);
    ushort_t* WoF   = (ushort_t*)take((size_t)HIDD * NCLSD * 2);
    float* e1v  = (float*)take(NNODE * 4);
    float* e2v  = (float*)take(NNODE * 4);
    float* t1v  = (float*)take(NNODE * 4);
    float* t2v  = (float*)take(NNODE * 4);
    float* o1v  = (float*)take(NNODE * 4);
    float* o2v  = (float*)take(NNODE * 4);
    float* wg1  = (float*)take(FEATD * 4);
    float* wg2  = (float*)take(FEATD * 4);
    float* wt1  = (float*)take(HIDD * 4);
    float* wt2  = (float*)take(HIDD * 4);
    float* scal = (float*)take(256);
    float* e2m = scal;
    float* out2 = Wh2;   // fallback alias

    size_t pbytes = (size_t)NNODE * NNODE * 2;
    bool bigws = (off + pbytes + NNODE * 4 + 4096) <= ws_size;
    ushort_t* Pbuf  = bigws ? (ushort_t*)take(pbytes) : nullptr;
    float*    lsumv = bigws ? (float*)take(NNODE * 4) : nullptr;

    // fused weight prep
    k_prep<<<dim3(400), dim3(256), 0, stream>>>(Wg, ag, Wt, at, Wo, WgF, WoF, wg1, wg2, wt1, wt2);
    // fused X fragmentize + layer-1 scores
    k_xprep<<<dim3(NNODE/16), dim3(256), 0, stream>>>(X, wg1, wg2, XF, e1v, e2v);
    if (bigws){
        // overlapped: gemm_xw (even bids) + pgen (odd bids)
        k_mid<<<dim3(NNODE/16 * 2), dim3(512), 0, stream>>>(XF, WgF, VF, adj, e1v, e2v, Pbuf, lsumv, (u8_t*)maskb);
        k_gat1g<<<dim3(NNODE/64 * 8), dim3(256), 0, stream>>>(Pbuf, lsumv, VF, res);
    } else {
        k_gemm_xw<<<dim3(NNODE/16), dim3(512), 0, stream>>>(XF, WgF, VF);
        k_max<<<dim3(1), dim3(1024), 0, stream>>>(e2v, NNODE, e2m);
        k_adjmask<<<dim3(2048), dim3(256), 0, stream>>>(adj, maskb);
        k_gat1<<<dim3(NNODE/16 * 2), dim3(256), 0, stream>>>(maskb, e1v, e2v, e2m, VF, res);
    }
    // overlapped: gemm_out (b<96) + rowvec2(res·wt) (b>=96)
    k_l2prep<<<dim3(96 + NNODE/4), dim3(256), 0, stream>>>(res, WoF, Wh2, VF2, wt1, wt2, t1v, t2v);
    k_rowvec2_f32<<<dim3(NNODE/4), dim3(256), 0, stream>>>(Wh2, ao, ao + NCLSD, o1v, o2v, NCLSD);
    // GAT layer 2 (+internal maxes, fused log_softmax)
    k_gat2<<<dim3(NNODE/16), dim3(512), 0, stream>>>(maskb, o1v, o2v, t1v, t2v, VF2, out);
    (void)out2; (void)k_logsoftmax;
}

// Round 22
// 242.687 us; speedup vs baseline: 1.0617x; 1.0617x over previous
//
#include <hip/hip_runtime.h>

#define NNODE 6144
#define FEATD 512
#define HIDD  512
#define NCLSD 64
#define NMSK  (NNODE/64)   // 96 mask words per row
#define NKT   (NNODE/32)   // 192 k-tiles (node dim)
#define NKTX  (FEATD/32)   // 16 k-tiles (feature dim)
#define LALPHA 0.2f

typedef unsigned short ushort_t;
typedef unsigned char u8_t;
typedef unsigned long long u64_t;
typedef short bf16x8 __attribute__((ext_vector_type(8)));
typedef float f32x4 __attribute__((ext_vector_type(4)));

__device__ __forceinline__ float lrelu(float x){ return x > 0.f ? x : LALPHA * x; }

__device__ __forceinline__ ushort_t f2b(float x){
    union { float f; unsigned u; } v; v.f = x;
    unsigned r = v.u + 0x7fffu + ((v.u >> 16) & 1u);
    return (ushort_t)(r >> 16);
}
__device__ __forceinline__ float b2f(ushort_t u){
    union { unsigned u; float f; } v; v.u = ((unsigned)u) << 16; return v.f;
}

// Runtime C/D-layout calibration (round-8 validated)
__device__ __forceinline__ void calib_cd(int lm, int* qrow, int* vcol){
    bf16x8 ai, as;
    ushort_t vi = f2b((float)(lm + 1));
    ushort_t vs = f2b(0.03125f);
    #pragma unroll
    for (int e = 0; e < 8; e++){ ((ushort_t*)&ai)[e] = vi; ((ushort_t*)&as)[e] = vs; }
    f32x4 z = {0.f, 0.f, 0.f, 0.f};
    f32x4 d1 = __builtin_amdgcn_mfma_f32_16x16x32_bf16(ai, as, z, 0, 0, 0);
    f32x4 d2 = __builtin_amdgcn_mfma_f32_16x16x32_bf16(as, ai, z, 0, 0, 0);
    #pragma unroll
    for (int r = 0; r < 4; r++){
        qrow[r] = (int)(d1[r] + 0.5f) - 1;
        vcol[r] = (int)(d2[r] + 0.5f) - 1;
    }
}

// ---------------- adj (int32) -> bitmask (fallback path only) ----------------
__global__ void k_adjmask(const int* __restrict__ adj, u64_t* __restrict__ mask){
    int lane = threadIdx.x & 63;
    size_t wid = ((size_t)blockIdx.x * blockDim.x + threadIdx.x) >> 6;
    size_t nw = (size_t)NNODE * NNODE / 64;
    size_t stride = ((size_t)gridDim.x * blockDim.x) >> 6;
    for (size_t q = wid; q < nw; q += stride){
        int a = adj[q * 64 + lane];
        u64_t b = __ballot(a > 0);
        if (lane == 0) mask[q] = b;
    }
}

// ---------------- fold helper ----------------
__device__ __forceinline__ void fold_rows(const float* W, const float* a,
        float* out1, float* out2, int K, int blk, int tid){
    int row  = (blk * 256 + tid) >> 6;
    int lane = tid & 63;
    const float* wr = W + (size_t)row * K;
    float s1 = 0.f, s2 = 0.f;
    for (int c = lane; c < K; c += 64){ float w = wr[c]; s1 += w * a[c]; s2 += w * a[K + c]; }
    #pragma unroll
    for (int m = 32; m; m >>= 1){ s1 += __shfl_xor(s1, m); s2 += __shfl_xor(s2, m); }
    if (lane == 0){ out1[row] = s1; out2[row] = s2; }
}

// ---------------- fused prep: fold(Wg), fold(Wt), WgF, WoF ----------------
__global__ __launch_bounds__(256) void k_prep(const float* __restrict__ Wg,
        const float* __restrict__ ag, const float* __restrict__ Wt,
        const float* __restrict__ at, const float* __restrict__ Wo,
        ushort_t* __restrict__ WgF, ushort_t* __restrict__ WoF,
        float* __restrict__ wg1, float* __restrict__ wg2,
        float* __restrict__ wt1, float* __restrict__ wt2){
    int b = blockIdx.x, tid = threadIdx.x;
    if (b < 128){
        fold_rows(Wg, ag, wg1, wg2, HIDD, b, tid);
    } else if (b < 256){
        fold_rows(Wt, at, wt1, wt2, HIDD, b - 128, tid);
    } else if (b < 384){
        int gid = (b - 256) * 256 + tid;
        int l = gid & 63, unit = gid >> 6;
        int ci = unit / NKTX, ki = unit - ci * NKTX;
        int lm = l & 15, lh = l >> 4;
        bf16x8 pk;
        #pragma unroll
        for (int e = 0; e < 8; e++)
            ((ushort_t*)&pk)[e] = f2b(Wg[(size_t)(ki*32 + lh*8 + e) * HIDD + ci*16 + lm]);
        *(bf16x8*)(WgF + (size_t)unit * 512 + (size_t)l * 8) = pk;
    } else {
        int gid = (b - 384) * 256 + tid;
        if (gid >= (NCLSD/16) * NKTX * 64) return;
        int l = gid & 63, unit = gid >> 6;
        int ci = unit / NKTX, ki = unit - ci * NKTX;
        int lm = l & 15, lh = l >> 4;
        bf16x8 pk;
        #pragma unroll
        for (int e = 0; e < 8; e++)
            ((ushort_t*)&pk)[e] = f2b(Wo[(size_t)(ki*32 + lh*8 + e) * NCLSD + ci*16 + lm]);
        *(bf16x8*)(WoF + (size_t)unit * 512 + (size_t)l * 8) = pk;
    }
}

// ---------------- o1/o2 = A @ {v1,v2}  (one wave per row) ----------------
__global__ void k_rowvec2_f32(const float* __restrict__ A, const float* __restrict__ v1,
                              const float* __restrict__ v2, float* __restrict__ o1,
                              float* __restrict__ o2, int K){
    int row  = (blockIdx.x * blockDim.x + threadIdx.x) >> 6;
    int lane = threadIdx.x & 63;
    const float* r = A + (size_t)row * K;
    float s1 = 0.f, s2 = 0.f;
    for (int c = lane; c < K; c += 64){ float x = r[c]; s1 += x * v1[c]; s2 += x * v2[c]; }
    #pragma unroll
    for (int m = 32; m; m >>= 1){ s1 += __shfl_xor(s1, m); s2 += __shfl_xor(s2, m); }
    if (lane == 0){ o1[row] = s1; o2[row] = s2; }
}

// ---------------- *out = max(x[0..n))  (fallback path only) ----------------
__global__ void k_max(const float* __restrict__ x, int n, float* __restrict__ out){
    __shared__ float sm[16];
    float m = -3.0e38f;
    for (int i = threadIdx.x; i < n; i += blockDim.x) m = fmaxf(m, x[i]);
    #pragma unroll
    for (int s = 32; s; s >>= 1) m = fmaxf(m, __shfl_xor(m, s));
    if ((threadIdx.x & 63) == 0) sm[threadIdx.x >> 6] = m;
    __syncthreads();
    if (threadIdx.x == 0){
        float mm = sm[0];
        for (int i = 1; i < (int)(blockDim.x >> 6); i++) mm = fmaxf(mm, sm[i]);
        *out = mm;
    }
}

// ---------------- fused: X -> XF fragments + e1/e2 scores ----------------
__global__ __launch_bounds__(256) void k_xprep(const float* __restrict__ X,
        const float* __restrict__ wg1, const float* __restrict__ wg2,
        ushort_t* __restrict__ XF, float* __restrict__ e1, float* __restrict__ e2){
    __shared__ float w1s[FEATD], w2s[FEATD];
    int ri = blockIdx.x;
    int tid = threadIdx.x;
    int r = tid >> 4, q = tid & 15;
    for (int k = tid; k < FEATD; k += 256){ w1s[k] = wg1[k]; w2s[k] = wg2[k]; }
    __syncthreads();
    const float* xp = X + (size_t)(ri * 16 + r) * FEATD;
    ushort_t* xb = XF + (size_t)ri * NKTX * 512;
    float s1 = 0.f, s2 = 0.f;
    for (int j0 = 0; j0 < FEATD; j0 += 128){
        int j = j0 + q * 8;
        float4 fA = *(const float4*)(xp + j);
        float4 fB = *(const float4*)(xp + j + 4);
        float xa[8] = {fA.x, fA.y, fA.z, fA.w, fB.x, fB.y, fB.z, fB.w};
        bf16x8 pk;
        #pragma unroll
        for (int e = 0; e < 8; e++){
            ((ushort_t*)&pk)[e] = f2b(xa[e]);
            s1 += xa[e] * w1s[j + e];
            s2 += xa[e] * w2s[j + e];
        }
        int ki = j >> 5;
        int lh = (j >> 3) & 3;
        *(bf16x8*)(xb + ((size_t)ki * 512 + (size_t)(r + (lh << 4)) * 8)) = pk;
    }
    #pragma unroll
    for (int o = 8; o; o >>= 1){ s1 += __shfl_xor(s1, o); s2 += __shfl_xor(s2, o); }
    if (q == 0){
        int row = ri * 16 + r;
        e1[row] = s1; e2[row] = s2;
    }
}

// ---------------- Wh1 = X @ Wg via MFMA -> VF fragments ----------------
__global__ __launch_bounds__(512) void k_gemm_xw(const ushort_t* __restrict__ XF,
        const ushort_t* __restrict__ WgF, ushort_t* __restrict__ VF){
    int ri = blockIdx.x;
    int i0 = ri * 16;
    int w = threadIdx.x >> 6, l = threadIdx.x & 63, lm = l & 15;
    int c0 = w * 64;
    int qrow[4], vcol[4];
    calib_cd(lm, qrow, vcol);
    f32x4 acc[4] = {};
    const ushort_t* Ap = XF + (size_t)ri * NKTX * 512 + l * 8;
    const ushort_t* Bp[4];
    #pragma unroll
    for (int t = 0; t < 4; t++)
        Bp[t] = WgF + (size_t)((c0 >> 4) + t) * NKTX * 512 + l * 8;
    for (int ki = 0; ki < NKTX; ki++){
        bf16x8 af = *(const bf16x8*)(Ap + (size_t)ki * 512);
        #pragma unroll
        for (int t = 0; t < 4; t++){
            bf16x8 bf = *(const bf16x8*)(Bp[t] + (size_t)ki * 512);
            acc[t] = __builtin_amdgcn_mfma_f32_16x16x32_bf16(af, bf, acc[t], 0, 0, 0);
        }
    }
    #pragma unroll
    for (int t = 0; t < 4; t++){
        int ci = (c0 >> 4) + t;
        #pragma unroll
        for (int r = 0; r < 4; r++){
            int node = i0 + qrow[r];
            size_t vo = ((size_t)ci * NKT + (node >> 5)) * 512
                      + (size_t)(vcol[r] + ((node >> 3) & 3) * 16) * 8 + (node & 7);
            VF[vo] = f2b(acc[t][r]);
        }
    }
}

// ---------------- P-gen v3 (round-20 proven): 256 thr, block-local e2max ----------------
__global__ __launch_bounds__(256) void k_pgen(const int* __restrict__ adj,
        const float* __restrict__ e1, const float* __restrict__ e2,
        ushort_t* __restrict__ PF, float* __restrict__ lsum, u8_t* __restrict__ mask8){
    __shared__ float e2s[NNODE];
    __shared__ float mred[4];
    int ri = blockIdx.x;
    int i0 = ri * 16;
    int tid = threadIdx.x;
    int r = tid >> 4, q = tid & 15;
    for (int k = tid; k < NNODE; k += 256) e2s[k] = e2[k];
    __syncthreads();
    float mx = -3.0e38f;
    for (int k = tid; k < NNODE; k += 256) mx = fmaxf(mx, e2s[k]);
    #pragma unroll
    for (int o = 32; o; o >>= 1) mx = fmaxf(mx, __shfl_xor(mx, o));
    if ((tid & 63) == 0) mred[tid >> 6] = mx;
    __syncthreads();
    float e2m = fmaxf(fmaxf(mred[0], mred[1]), fmaxf(mred[2], mred[3]));
    float e1i = e1[i0 + r];
    float M = lrelu(e1i + e2m);   // exact upper bound (softmax shift-invariant)
    float rsum = 0.f;
    ushort_t* pfb = PF + (size_t)ri * NKT * 512;
    const int* adjp = adj + (size_t)(i0 + r) * NNODE;
    u8_t* mrow = mask8 + (size_t)(i0 + r) * (NMSK * 8);
    for (int j0 = 0; j0 < NNODE; j0 += 128){
        int j = j0 + q * 8;
        int4 a0 = *(const int4*)(adjp + j);
        int4 a1 = *(const int4*)(adjp + j + 4);
        int av[8] = {a0.x, a0.y, a0.z, a0.w, a1.x, a1.y, a1.z, a1.w};
        float4 fA = *(const float4*)&e2s[j];
        float4 fB = *(const float4*)&e2s[j + 4];
        float ea[8] = {fA.x, fA.y, fA.z, fA.w, fB.x, fB.y, fB.z, fB.w};
        bf16x8 pk;
        unsigned byte = 0;
        #pragma unroll
        for (int e = 0; e < 8; e++){
            int bit = av[e] > 0;
            byte |= (unsigned)bit << e;
            float p = bit ? __expf(lrelu(e1i + ea[e]) - M) : 0.f;
            ushort_t pb = f2b(p);
            ((ushort_t*)&pk)[e] = pb;
            rsum += b2f(pb);
        }
        mrow[j >> 3] = (u8_t)byte;
        int ki = j >> 5;
        int lh = (j >> 3) & 3;
        *(bf16x8*)(pfb + ((size_t)ki * 512 + (size_t)(r + (lh << 4)) * 8)) = pk;
    }
    #pragma unroll
    for (int o = 8; o; o >>= 1) rsum += __shfl_xor(rsum, o);
    if (q == 0) lsum[i0 + r] = rsum;
}

// ---------------- k_l2prep: gemm_out (b<96) + rowvec2(res·wt) (b>=96) ----------------
__global__ __launch_bounds__(256) void k_l2prep(const float* __restrict__ res,
        const ushort_t* __restrict__ WoF, float* __restrict__ Wh2,
        ushort_t* __restrict__ VF2, const float* __restrict__ wt1,
        const float* __restrict__ wt2, float* __restrict__ t1v, float* __restrict__ t2v){
    int b = blockIdx.x, tid = threadIdx.x;
    if (b >= 96){
        int row  = ((b - 96) * 256 + tid) >> 6;
        int lane = tid & 63;
        const float* r = res + (size_t)row * HIDD;
        float s1 = 0.f, s2 = 0.f;
        for (int c = lane; c < HIDD; c += 64){ float x = r[c]; s1 += x * wt1[c]; s2 += x * wt2[c]; }
        #pragma unroll
        for (int m = 32; m; m >>= 1){ s1 += __shfl_xor(s1, m); s2 += __shfl_xor(s2, m); }
        if (lane == 0){ t1v[row] = s1; t2v[row] = s2; }
        return;
    }
    int w = tid >> 6, l = tid & 63, lm = l & 15, lh = l >> 4;
    int i0 = b * 64 + w * 16;
    int qrow[4], vcol[4];
    calib_cd(lm, qrow, vcol);
    f32x4 acc[4] = {};
    const float* ap = res + (size_t)(i0 + lm) * HIDD + lh * 8;
    for (int k0 = 0; k0 < HIDD; k0 += 32){
        int ki = k0 >> 5;
        float4 x0 = *(const float4*)(ap + k0);
        float4 x1 = *(const float4*)(ap + k0 + 4);
        float xa[8] = {x0.x, x0.y, x0.z, x0.w, x1.x, x1.y, x1.z, x1.w};
        bf16x8 af;
        #pragma unroll
        for (int e = 0; e < 8; e++) ((ushort_t*)&af)[e] = f2b(xa[e]);
        #pragma unroll
        for (int t = 0; t < 4; t++){
            bf16x8 bf = *(const bf16x8*)(WoF + (size_t)(t * NKTX + ki) * 512 + l * 8);
            acc[t] = __builtin_amdgcn_mfma_f32_16x16x32_bf16(af, bf, acc[t], 0, 0, 0);
        }
    }
    #pragma unroll
    for (int t = 0; t < 4; t++){
        #pragma unroll
        for (int r = 0; r < 4; r++){
            int node = i0 + qrow[r], col = t*16 + vcol[r];
            float v = acc[t][r];
            Wh2[(size_t)node * NCLSD + col] = v;
            size_t vo = ((size_t)t * NKT + (node >> 5)) * 512
                      + (size_t)(vcol[r] + ((node >> 3) & 3) * 16) * 8 + (node & 7);
            VF2[vo] = f2b(v);
        }
    }
}

// ---------------- GAT1 GEMM: XCD swizzle + banked 2-deep loop ----------------
__global__ __launch_bounds__(256) void k_gat1g(const ushort_t* __restrict__ PF,
        const float* __restrict__ lsum, const ushort_t* __restrict__ VF,
        float* __restrict__ res){
    int bid = blockIdx.x;
    int xcd = bid & 7;
    int k   = bid >> 3;
    int c8  = k & 7;
    int rg  = (k >> 3) * 8 + xcd;
    int tid = threadIdx.x;
    int w = tid >> 6, l = tid & 63, lm = l & 15;
    int ri = rg * 4 + w;
    int i0 = ri * 16;
    int cbase = c8 * 64;
    int qrow[4], vcol[4];
    calib_cd(lm, qrow, vcol);
    f32x4 acc[4] = {};
    const ushort_t* Ap = PF + (size_t)ri * NKT * 512 + l * 8;
    const ushort_t* Vp[4];
    #pragma unroll
    for (int t = 0; t < 4; t++)
        Vp[t] = VF + (size_t)(c8 * 4 + t) * NKT * 512 + l * 8;
    bf16x8 aA, aB, vA[4], vB[4];
    aA = *(const bf16x8*)(Ap);
    #pragma unroll
    for (int t = 0; t < 4; t++) vA[t] = *(const bf16x8*)(Vp[t]);
    for (int kt = 0; kt < NKT; kt += 2){
        size_t ob = (size_t)(kt + 1) * 512;
        aB = *(const bf16x8*)(Ap + ob);
        #pragma unroll
        for (int t = 0; t < 4; t++) vB[t] = *(const bf16x8*)(Vp[t] + ob);
        #pragma unroll
        for (int t = 0; t < 4; t++)
            acc[t] = __builtin_amdgcn_mfma_f32_16x16x32_bf16(aA, vA[t], acc[t], 0, 0, 0);
        int k2 = (kt + 2 < NKT) ? kt + 2 : 0;
        size_t oa = (size_t)k2 * 512;
        aA = *(const bf16x8*)(Ap + oa);
        #pragma unroll
        for (int t = 0; t < 4; t++) vA[t] = *(const bf16x8*)(Vp[t] + oa);
        #pragma unroll
        for (int t = 0; t < 4; t++)
            acc[t] = __builtin_amdgcn_mfma_f32_16x16x32_bf16(aB, vB[t], acc[t], 0, 0, 0);
    }
    float den[4];
    #pragma unroll
    for (int r = 0; r < 4; r++) den[r] = lsum[i0 + qrow[r]];
    #pragma unroll
    for (int t = 0; t < 4; t++){
        #pragma unroll
        for (int r = 0; r < 4; r++){
            int row = qrow[r];
            int col = cbase + t*16 + vcol[r];
            float v = acc[t][r] / den[r];
            v = v > 0.f ? v : expm1f(v);   // elu
            res[(size_t)(i0 + row) * HIDD + col] = v;
        }
    }
}

// ---------------- GAT layer 1 fallback (register P, VF layout) ----------------
__global__ __launch_bounds__(256) void k_gat1(const u64_t* __restrict__ mask,
        const float* __restrict__ e1, const float* __restrict__ e2,
        const float* __restrict__ e2max,
        const ushort_t* __restrict__ VF, float* __restrict__ res){
    __shared__ __align__(16) float e2s[NNODE];
    __shared__ u64_t msk[16][NMSK + 1];
    int bid = blockIdx.x;
    int b8 = bid & 7, a = bid >> 3;
    int ch = b8 >> 2;
    int rg = a * 4 + (b8 & 3);
    int i0 = rg * 16;
    int tid = threadIdx.x;
    int w = tid >> 6, l = tid & 63, lm = l & 15, lh = l >> 4;
    int cbase = ch * 256 + w * 64;
    int qrow[4], vcol[4];
    calib_cd(lm, qrow, vcol);
    for (int k = tid; k < NNODE; k += 256) e2s[k] = e2[k];
    for (int k = tid; k < 16 * NMSK; k += 256) msk[k / NMSK][k % NMSK] = mask[(size_t)i0 * NMSK + k];
    __syncthreads();
    float e1i = e1[i0 + lm];
    float M = lrelu(e1i + *e2max);
    float lsum = 0.f;
    f32x4 acc[4] = {};
    const ushort_t* Vp[4];
    #pragma unroll
    for (int t = 0; t < 4; t++)
        Vp[t] = VF + (size_t)((cbase >> 4) + t) * NKT * 512 + l * 8;
    bf16x8 vc[4][2], vn[4][2];
    #pragma unroll
    for (int t = 0; t < 4; t++)
        #pragma unroll
        for (int h = 0; h < 2; h++) vc[t][h] = *(const bf16x8*)(Vp[t] + h * 512);
    for (int j0 = 0; j0 < NNODE; j0 += 64){
        u64_t word = msk[lm][j0 >> 6];
        int jn = j0 + 64;
        if (jn < NNODE){
            size_t nb = (size_t)(jn >> 5) * 512;
            #pragma unroll
            for (int t = 0; t < 4; t++)
                #pragma unroll
                for (int h = 0; h < 2; h++) vn[t][h] = *(const bf16x8*)(Vp[t] + nb + h * 512);
        }
        #pragma unroll
        for (int h = 0; h < 2; h++){
            int jb = j0 + h*32 + lh*8;
            float4 fA = *(const float4*)&e2s[jb];
            float4 fB = *(const float4*)&e2s[jb + 4];
            float ea[8] = {fA.x, fA.y, fA.z, fA.w, fB.x, fB.y, fB.z, fB.w};
            int sh = h*32 + lh*8;
            bf16x8 pk;
            float ls = 0.f;
            #pragma unroll
            for (int e = 0; e < 8; e++){
                float p = ((word >> (sh + e)) & 1ull) ? __expf(lrelu(e1i + ea[e]) - M) : 0.f;
                ushort_t pb = f2b(p);
                ((ushort_t*)&pk)[e] = pb;
                ls += b2f(pb);
            }
            lsum += ls;
            #pragma unroll
            for (int t = 0; t < 4; t++)
                acc[t] = __builtin_amdgcn_mfma_f32_16x16x32_bf16(pk, vc[t][h], acc[t], 0, 0, 0);
        }
        #pragma unroll
        for (int t = 0; t < 4; t++)
            #pragma unroll
            for (int h = 0; h < 2; h++) vc[t][h] = vn[t][h];
    }
    lsum += __shfl_xor(lsum, 16);
    lsum += __shfl_xor(lsum, 32);
    #pragma unroll
    for (int t = 0; t < 4; t++){
        #pragma unroll
        for (int r = 0; r < 4; r++){
            float den = __shfl(lsum, qrow[r]);
            int row = qrow[r];
            int col = cbase + t*16 + vcol[r];
            float v = acc[t][r] / den;
            v = v > 0.f ? v : expm1f(v);
            res[(size_t)(i0 + row) * HIDD + col] = v;
        }
    }
}

// ---------------- GAT layer 2 + fused log_softmax (internal maxes) ----------------
#define JSPAN (NNODE/8)
__global__ __launch_bounds__(512) void k_gat2(const u64_t* __restrict__ mask,
        const float* __restrict__ o1, const float* __restrict__ o2,
        const float* __restrict__ t1, const float* __restrict__ t2,
        const ushort_t* __restrict__ VF2, float* __restrict__ out){
    __shared__ float accs[8][16][64];
    __shared__ float lsums[8][16];
    __shared__ u64_t msk[16][NMSK + 1];
    __shared__ float mred[16];
    int i0 = blockIdx.x * 16;
    int tid = threadIdx.x;
    int w = tid >> 6, l = tid & 63, lm = l & 15, lh = l >> 4;
    for (int k = tid; k < 16 * NMSK; k += 512) msk[k / NMSK][k % NMSK] = mask[(size_t)i0 * NMSK + k];
    float mo = -3.0e38f, mt = -3.0e38f;
    for (int k = tid; k < NNODE; k += 512){ mo = fmaxf(mo, o2[k]); mt = fmaxf(mt, t2[k]); }
    #pragma unroll
    for (int o = 32; o; o >>= 1){ mo = fmaxf(mo, __shfl_xor(mo, o)); mt = fmaxf(mt, __shfl_xor(mt, o)); }
    if (l == 0){ mred[w * 2] = mo; mred[w * 2 + 1] = mt; }
    __syncthreads();
    float o2m = -3.0e38f, t2m = -3.0e38f;
    #pragma unroll
    for (int q = 0; q < 8; q++){ o2m = fmaxf(o2m, mred[q * 2]); t2m = fmaxf(t2m, mred[q * 2 + 1]); }
    int qrow[4], vcol[4];
    calib_cd(lm, qrow, vcol);
    int jbase = w * JSPAN;
    float o1v = o1[i0 + lm], t1v = t1[i0 + lm];
    float M = lrelu(o1v + o2m) + lrelu(t1v + t2m);
    float lsum = 0.f;
    f32x4 acc[4] = {};
    const float* o2p = o2 + jbase + lh * 8;
    const float* t2p = t2 + jbase + lh * 8;
    float4 oA = *(const float4*)(o2p), oB = *(const float4*)(o2p + 4);
    float4 tA = *(const float4*)(t2p), tB = *(const float4*)(t2p + 4);
    const u8_t* mrow = (const u8_t*)&msk[lm][0];
    const ushort_t* Vp[4];
    #pragma unroll
    for (int t = 0; t < 4; t++)
        Vp[t] = VF2 + (size_t)t * NKT * 512 + (size_t)(jbase >> 5) * 512 + l * 8;
    bf16x8 vcur[4], vnxt[4];
    #pragma unroll
    for (int t = 0; t < 4; t++) vcur[t] = *(const bf16x8*)(Vp[t]);

    for (int js = 0; js < JSPAN; js += 32){
        unsigned b8v = mrow[(jbase + js + lh * 8) >> 3];
        float oa[8] = {oA.x, oA.y, oA.z, oA.w, oB.x, oB.y, oB.z, oB.w};
        float ta[8] = {tA.x, tA.y, tA.z, tA.w, tB.x, tB.y, tB.z, tB.w};
        bf16x8 pk;
        float ls = 0.f;
        #pragma unroll
        for (int e = 0; e < 8; e++){
            float p = ((b8v >> e) & 1u) ?
                      __expf(lrelu(o1v + oa[e]) + lrelu(t1v + ta[e]) - M) : 0.f;
            ushort_t pb = f2b(p);
            ((ushort_t*)&pk)[e] = pb;
            ls += b2f(pb);
        }
        lsum += ls;
        int jn = js + 32;
        if (jn < JSPAN){
            oA = *(const float4*)(o2p + jn); oB = *(const float4*)(o2p + jn + 4);
            tA = *(const float4*)(t2p + jn); tB = *(const float4*)(t2p + jn + 4);
            #pragma unroll
            for (int t = 0; t < 4; t++)
                vnxt[t] = *(const bf16x8*)(Vp[t] + (size_t)(jn >> 5) * 512);
        }
        #pragma unroll
        for (int t = 0; t < 4; t++)
            acc[t] = __builtin_amdgcn_mfma_f32_16x16x32_bf16(pk, vcur[t], acc[t], 0, 0, 0);
        #pragma unroll
        for (int t = 0; t < 4; t++) vcur[t] = vnxt[t];
    }
    lsum += __shfl_xor(lsum, 16);
    lsum += __shfl_xor(lsum, 32);
    if (lh == 0) lsums[w][lm] = lsum;
    #pragma unroll
    for (int t = 0; t < 4; t++)
        #pragma unroll
        for (int r = 0; r < 4; r++)
            accs[w][qrow[r]][t*16 + vcol[r]] = acc[t][r];
    __syncthreads();
    #pragma unroll
    for (int rr = 0; rr < 2; rr++){
        int row = w * 2 + rr;
        float den = 0.f, v = 0.f;
        #pragma unroll
        for (int q = 0; q < 8; q++){ den += lsums[q][row]; v += accs[q][row][l]; }
        float val = v / den;
        float mx = val;
        #pragma unroll
        for (int o = 32; o; o >>= 1) mx = fmaxf(mx, __shfl_xor(mx, o));
        float ex = __expf(val - mx);
        #pragma unroll
        for (int o = 32; o; o >>= 1) ex += __shfl_xor(ex, o);
        out[(size_t)(i0 + row) * NCLSD + l] = val - mx - logf(ex);
    }
}

// ---------------- row-wise log_softmax (fallback path only) ----------------
__global__ void k_logsoftmax(const float* __restrict__ out2, float* __restrict__ out){
    int w = threadIdx.x >> 6, l = threadIdx.x & 63;
    int row = blockIdx.x * 4 + w;
    float v = out2[(size_t)row * NCLSD + l];
    float mx = v;
    #pragma unroll
    for (int o = 32; o; o >>= 1) mx = fmaxf(mx, __shfl_xor(mx, o));
    float ex = __expf(v - mx);
    #pragma unroll
    for (int o = 32; o; o >>= 1) ex += __shfl_xor(ex, o);
    out[(size_t)row * NCLSD + l] = v - mx - logf(ex);
}

// ---------------- launch ----------------
extern "C" void kernel_launch(void* const* d_in, const int* in_sizes, int n_in,
                              void* d_out, int out_size, void* d_ws, size_t ws_size,
                              hipStream_t stream){
    const float* X   = (const float*)d_in[0];
    const int*   adj = (const int*)d_in[1];
    const float* Wg  = (const float*)d_in[2];
    const float* ag  = (const float*)d_in[3];
    const float* Wt  = (const float*)d_in[4];
    const float* at  = (const float*)d_in[5];
    const float* Wo  = (const float*)d_in[6];
    const float* ao  = (const float*)d_in[7];
    float* out = (float*)d_out;

    char* ws = (char*)d_ws;
    size_t off = 0;
    auto take = [&](size_t n){ char* p = ws + off; off = (off + n + 255) & ~(size_t)255; return p; };
    u64_t*    maskb = (u64_t*)take((size_t)NNODE * NMSK * 8);
    ushort_t* VF    = (ushort_t*)take((size_t)HIDD * NNODE * 2);
    float*    res   = (float*)take((size_t)NNODE * HIDD * 4);
    float*    Wh2   = (float*)take((size_t)NNODE * NCLSD * 4);
    ushort_t* VF2   = (ushort_t*)take((size_t)NCLSD * NNODE * 2);
    ushort_t* XF    = (ushort_t*)take((size_t)NNODE * FEATD * 2);
    ushort_t* WgF   = (ushort_t*)take((size_t)FEATD * HIDD * 2);
    ushort_t* WoF   = (ushort_t*)take((size_t)HIDD * NCLSD * 2);
    float* e1v  = (float*)take(NNODE * 4);
    float* e2v  = (float*)take(NNODE * 4);
    float* t1v  = (float*)take(NNODE * 4);
    float* t2v  = (float*)take(NNODE * 4);
    float* o1v  = (float*)take(NNODE * 4);
    float* o2v  = (float*)take(NNODE * 4);
    float* wg1  = (float*)take(FEATD * 4);
    float* wg2  = (float*)take(FEATD * 4);
    float* wt1  = (float*)take(HIDD * 4);
    float* wt2  = (float*)take(HIDD * 4);
    float* scal = (float*)take(256);
    float* e2m = scal;
    float* out2 = Wh2;   // fallback alias

    size_t pbytes = (size_t)NNODE * NNODE * 2;
    bool bigws = (off + pbytes + NNODE * 4 + 4096) <= ws_size;
    ushort_t* Pbuf  = bigws ? (ushort_t*)take(pbytes) : nullptr;
    float*    lsumv = bigws ? (float*)take(NNODE * 4) : nullptr;

    // fused weight prep
    k_prep<<<dim3(400), dim3(256), 0, stream>>>(Wg, ag, Wt, at, Wo, WgF, WoF, wg1, wg2, wt1, wt2);
    // fused X fragmentize + layer-1 scores
    k_xprep<<<dim3(NNODE/16), dim3(256), 0, stream>>>(X, wg1, wg2, XF, e1v, e2v);
    // Wh1 via MFMA
    k_gemm_xw<<<dim3(NNODE/16), dim3(512), 0, stream>>>(XF, WgF, VF);
    // GAT layer 1
    if (bigws){
        k_pgen<<<dim3(NNODE/16), dim3(256), 0, stream>>>(adj, e1v, e2v, Pbuf, lsumv, (u8_t*)maskb);
        k_gat1g<<<dim3(NNODE/64 * 8), dim3(256), 0, stream>>>(Pbuf, lsumv, VF, res);
    } else {
        k_max<<<dim3(1), dim3(1024), 0, stream>>>(e2v, NNODE, e2m);
        k_adjmask<<<dim3(2048), dim3(256), 0, stream>>>(adj, maskb);
        k_gat1<<<dim3(NNODE/16 * 2), dim3(256), 0, stream>>>(maskb, e1v, e2v, e2m, VF, res);
    }
    // overlapped: gemm_out (b<96) + rowvec2(res·wt) (b>=96)
    k_l2prep<<<dim3(96 + NNODE/4), dim3(256), 0, stream>>>(res, WoF, Wh2, VF2, wt1, wt2, t1v, t2v);
    k_rowvec2_f32<<<dim3(NNODE/4), dim3(256), 0, stream>>>(Wh2, ao, ao + NCLSD, o1v, o2v, NCLSD);
    // GAT layer 2 (+internal maxes, fused log_softmax)
    k_gat2<<<dim3(NNODE/16), dim3(512), 0, stream>>>(maskb, o1v, o2v, t1v, t2v, VF2, out);
    (void)out2; (void)k_logsoftmax;
}